// Round 1
// baseline (120.885 us; speedup 1.0000x reference)
//
#include <hip/hip_runtime.h>
#include <hip/hip_bf16.h>

// y[n,g,h] = sum_k x[n,g,k] * H[g,k,h]
// x: [ntok, 4096] fp32, H: [64, 64, 64] fp32, y: [ntok, 4096] fp32.
// Memory-bound (16 FLOP/byte < 25 crossover). bf16 MFMA, fp32 accum/out.

#define DIM 4096
#define NG   64   // groups per token
#define GSZ  64   // group size
#define TOK_PER_BLK 256

typedef __bf16 bf16x8 __attribute__((ext_vector_type(8)));
typedef float  f32x4  __attribute__((ext_vector_type(4)));

__global__ __launch_bounds__(256, 4)
void hh_mfma_kernel(const float* __restrict__ x, const float* __restrict__ H,
                    float* __restrict__ y, int ntok) {
    __shared__ __align__(16) float Hl[GSZ * GSZ];   // 16 KiB: H_g staged fp32

    const int g    = blockIdx.x & (NG - 1);
    const int tb   = blockIdx.x >> 6;
    const int tid  = threadIdx.x;
    const int lane = tid & 63;
    const int wave = tid >> 6;

    // ---- stage H_g into LDS, coalesced float4 ----
    const float* __restrict__ Hg = H + (size_t)g * (GSZ * GSZ);
    #pragma unroll
    for (int i = 0; i < 4; ++i) {
        int idx = tid + i * 256;                         // 1024 float4s total
        ((f32x4*)Hl)[idx] = ((const f32x4*)Hg)[idx];
    }
    __syncthreads();

    // ---- build B fragments once (reused across all token tiles) ----
    // B[k][h]: lane holds B[kt*32 + (lane>>4)*8 + i][ht*16 + (lane&15)], i=0..7
    const int bcol = lane & 15;
    const int brow = (lane >> 4) * 8;
    bf16x8 bfrag[2][4];
    #pragma unroll
    for (int kt = 0; kt < 2; ++kt)
        #pragma unroll
        for (int ht = 0; ht < 4; ++ht)
            #pragma unroll
            for (int i = 0; i < 8; ++i)
                bfrag[kt][ht][i] =
                    (__bf16)Hl[(kt * 32 + brow + i) * GSZ + ht * 16 + bcol];

    // A: lane holds row lane&15, k = (lane>>4)*8 + i (8 consecutive fp32)
    const int arow  = lane & 15;
    const int acolk = (lane >> 4) * 8;
    // C/D: row = (lane>>4)*4 + j, col = lane&15   [measured m89/m91]
    const int crow0 = (lane >> 4) * 4;
    const int ccol  = lane & 15;

    const int tok0 = tb * TOK_PER_BLK + wave * 64;

    #pragma unroll
    for (int tt = 0; tt < 4; ++tt) {
        const int tbase = tok0 + tt * 16;

        // ---- load + convert A fragments (2 K-tiles of 16x32) ----
        bf16x8 afrag[2];
        const float* __restrict__ xp =
            x + (size_t)(tbase + arow) * DIM + g * GSZ + acolk;
        #pragma unroll
        for (int kt = 0; kt < 2; ++kt) {
            f32x4 lo = *(const f32x4*)(xp + kt * 32);
            f32x4 hi = *(const f32x4*)(xp + kt * 32 + 4);
            #pragma unroll
            for (int i = 0; i < 4; ++i) {
                afrag[kt][i]     = (__bf16)lo[i];
                afrag[kt][i + 4] = (__bf16)hi[i];
            }
        }

        // ---- 8 MFMAs: 4 h-tiles x 2 k-steps, fp32 accumulate ----
        f32x4 acc[4];
        #pragma unroll
        for (int ht = 0; ht < 4; ++ht) {
            acc[ht] = (f32x4){0.f, 0.f, 0.f, 0.f};
            acc[ht] = __builtin_amdgcn_mfma_f32_16x16x32_bf16(
                          afrag[0], bfrag[0][ht], acc[ht], 0, 0, 0);
            acc[ht] = __builtin_amdgcn_mfma_f32_16x16x32_bf16(
                          afrag[1], bfrag[1][ht], acc[ht], 0, 0, 0);
        }

        // ---- store: 16 lanes x 4B = 64B contiguous per store instr ----
        float* __restrict__ yp =
            y + (size_t)(tbase + crow0) * DIM + g * GSZ + ccol;
        #pragma unroll
        for (int ht = 0; ht < 4; ++ht)
            #pragma unroll
            for (int j = 0; j < 4; ++j)
                yp[(size_t)j * DIM + ht * 16] = acc[ht][j];
    }
}

extern "C" void kernel_launch(void* const* d_in, const int* in_sizes, int n_in,
                              void* d_out, int out_size, void* d_ws, size_t ws_size,
                              hipStream_t stream) {
    const float* x = (const float*)d_in[0];
    const float* H = (const float*)d_in[1];
    float* y = (float*)d_out;

    const int ntok = in_sizes[0] / DIM;             // 16384
    const int nblk = (ntok / TOK_PER_BLK) * NG;     // 64 * 64 = 4096

    hipLaunchKernelGGL(hh_mfma_kernel, dim3(nblk), dim3(256), 0, stream,
                       x, H, y, ntok);
}

// Round 2
// 102.738 us; speedup vs baseline: 1.1766x; 1.1766x over previous
//
#include <hip/hip_runtime.h>
#include <hip/hip_bf16.h>

// y[n,g,h] = sum_k x[n,g,k] * H[g,k,h]
// x: [ntok, 4096] fp32, H: [64, 64, 64] fp32, y: [ntok, 4096] fp32.
// Memory-bound. bf16 MFMA, fp32 accum. R1: LDS-transpose epilogue so each
// store instr writes 4x 256B fully-contiguous rows (was 16 scalar stores).

#define DIM 4096
#define NG   64   // groups per token
#define GSZ  64   // group size
#define TOK_PER_BLK 256
#define LDT  68   // transpose buffer row stride in floats (272B: 16B-aligned, pad kills conflicts)

typedef __bf16 bf16x8 __attribute__((ext_vector_type(8)));
typedef float  f32x4  __attribute__((ext_vector_type(4)));

__global__ __launch_bounds__(256, 4)
void hh_mfma_kernel(const float* __restrict__ x, const float* __restrict__ H,
                    float* __restrict__ y, int ntok) {
    __shared__ __align__(16) float Hl[GSZ * GSZ];        // 16 KiB
    __shared__ __align__(16) float Tl[4][16][LDT];       // 17 KiB, per-wave private

    const int g    = blockIdx.x & (NG - 1);
    const int tb   = blockIdx.x >> 6;
    const int tid  = threadIdx.x;
    const int lane = tid & 63;
    const int wave = tid >> 6;

    // ---- stage H_g into LDS, coalesced float4 ----
    const float* __restrict__ Hg = H + (size_t)g * (GSZ * GSZ);
    #pragma unroll
    for (int i = 0; i < 4; ++i) {
        int idx = tid + i * 256;                         // 1024 float4s total
        ((f32x4*)Hl)[idx] = ((const f32x4*)Hg)[idx];
    }
    __syncthreads();

    // ---- build B fragments once (reused across all token tiles) ----
    // B[k][h]: lane holds B[kt*32 + (lane>>4)*8 + i][ht*16 + (lane&15)], i=0..7
    const int bcol = lane & 15;
    const int brow = (lane >> 4) * 8;
    bf16x8 bfrag[2][4];
    #pragma unroll
    for (int kt = 0; kt < 2; ++kt)
        #pragma unroll
        for (int ht = 0; ht < 4; ++ht)
            #pragma unroll
            for (int i = 0; i < 8; ++i)
                bfrag[kt][ht][i] =
                    (__bf16)Hl[(kt * 32 + brow + i) * GSZ + ht * 16 + bcol];

    // A: lane holds row lane&15, k = (lane>>4)*8 + i (8 consecutive fp32)
    const int arow  = lane & 15;
    const int acolk = (lane >> 4) * 8;
    // C/D: row = (lane>>4)*4 + j, col = lane&15   [measured m89/m91]
    const int crow0 = (lane >> 4) * 4;
    const int ccol  = lane & 15;
    // store phase: lane -> (row = lane>>4 (+4i), float4 index = lane&15)
    const int srow  = lane >> 4;
    const int sq    = lane & 15;

    const int tok0 = tb * TOK_PER_BLK + wave * 64;
    float (* __restrict__ T)[LDT] = Tl[wave];

    #pragma unroll
    for (int tt = 0; tt < 4; ++tt) {
        const int tbase = tok0 + tt * 16;

        // ---- load + convert A fragments (2 K-tiles of 16x32) ----
        bf16x8 afrag[2];
        const float* __restrict__ xp =
            x + (size_t)(tbase + arow) * DIM + g * GSZ + acolk;
        #pragma unroll
        for (int kt = 0; kt < 2; ++kt) {
            f32x4 lo = *(const f32x4*)(xp + kt * 32);
            f32x4 hi = *(const f32x4*)(xp + kt * 32 + 4);
            #pragma unroll
            for (int i = 0; i < 4; ++i) {
                afrag[kt][i]     = (__bf16)lo[i];
                afrag[kt][i + 4] = (__bf16)hi[i];
            }
        }

        // ---- 8 MFMAs: 4 h-tiles x 2 k-steps, fp32 accumulate ----
        f32x4 acc[4];
        #pragma unroll
        for (int ht = 0; ht < 4; ++ht) {
            acc[ht] = (f32x4){0.f, 0.f, 0.f, 0.f};
            acc[ht] = __builtin_amdgcn_mfma_f32_16x16x32_bf16(
                          afrag[0], bfrag[0][ht], acc[ht], 0, 0, 0);
            acc[ht] = __builtin_amdgcn_mfma_f32_16x16x32_bf16(
                          afrag[1], bfrag[1][ht], acc[ht], 0, 0, 0);
        }

        // ---- transpose through per-wave LDS region (no barrier needed) ----
        #pragma unroll
        for (int ht = 0; ht < 4; ++ht)
            #pragma unroll
            for (int j = 0; j < 4; ++j)
                T[crow0 + j][ht * 16 + ccol] = acc[ht][j];

        // ---- store: 16 consecutive lanes write one 256B-contiguous row ----
        float* __restrict__ yp = y + (size_t)tbase * DIM + g * GSZ;
        #pragma unroll
        for (int i = 0; i < 4; ++i) {
            const int r = srow + 4 * i;
            f32x4 v = *(const f32x4*)&T[r][sq * 4];
            __builtin_nontemporal_store(v, (f32x4*)(yp + (size_t)r * DIM + sq * 4));
        }
    }
}

extern "C" void kernel_launch(void* const* d_in, const int* in_sizes, int n_in,
                              void* d_out, int out_size, void* d_ws, size_t ws_size,
                              hipStream_t stream) {
    const float* x = (const float*)d_in[0];
    const float* H = (const float*)d_in[1];
    float* y = (float*)d_out;

    const int ntok = in_sizes[0] / DIM;             // 16384
    const int nblk = (ntok / TOK_PER_BLK) * NG;     // 64 * 64 = 4096

    hipLaunchKernelGGL(hh_mfma_kernel, dim3(nblk), dim3(256), 0, stream,
                       x, H, y, ntok);
}

// Round 3
// 99.843 us; speedup vs baseline: 1.2108x; 1.0290x over previous
//
#include <hip/hip_runtime.h>
#include <hip/hip_bf16.h>

// y[n,g,h] = sum_k x[n,g,k] * H[g,k,h]
// x: [ntok, 4096] fp32, H: [64, 64, 64] fp32, y: [ntok, 4096] fp32.
// Memory/latency-bound. R2 fix: swapped-operand MFMA (D = H^T * x^T) so the
// accumulator's 4 row-values per lane are 4 CONSECUTIVE h's -> direct f32x4
// store, no LDS transpose. LDS = 16KB (H only) + VGPR<=64 -> 32 waves/CU.

#define DIM 4096
#define NG   64   // groups per token
#define GSZ  64   // group size
#define TOK_PER_BLK 256

typedef __bf16 bf16x8 __attribute__((ext_vector_type(8)));
typedef float  f32x4  __attribute__((ext_vector_type(4)));

__global__ __launch_bounds__(256, 8)
void hh_mfma_kernel(const float* __restrict__ x, const float* __restrict__ H,
                    float* __restrict__ y, int ntok) {
    __shared__ __align__(16) float Hl[GSZ * GSZ];        // 16 KiB

    const int g    = blockIdx.x & (NG - 1);
    const int tb   = blockIdx.x >> 6;
    const int tid  = threadIdx.x;
    const int lane = tid & 63;
    const int wave = tid >> 6;

    // ---- stage H_g into LDS, coalesced float4 ----
    const float* __restrict__ Hg = H + (size_t)g * (GSZ * GSZ);
    #pragma unroll
    for (int i = 0; i < 4; ++i) {
        int idx = tid + i * 256;                         // 1024 float4s total
        ((f32x4*)Hl)[idx] = ((const f32x4*)Hg)[idx];
    }
    __syncthreads();

    // ---- build H^T fragments (A operand) once, reused for all tiles ----
    // A[row][k]: lane holds A[lane&15][(lane>>4)*8+i]. Here A = H^T tile:
    // hfrag[kt][ht][i] = H^T[ht*16+(lane&15)][kt*32+(lane>>4)*8+i]
    //                  = Hl[(kt*32+(lane>>4)*8+i)*64 + ht*16 + (lane&15)]
    const int hcol = lane & 15;
    const int hrow = (lane >> 4) * 8;
    bf16x8 hfrag[2][4];
    #pragma unroll
    for (int kt = 0; kt < 2; ++kt)
        #pragma unroll
        for (int ht = 0; ht < 4; ++ht)
            #pragma unroll
            for (int i = 0; i < 8; ++i)
                hfrag[kt][ht][i] =
                    (__bf16)Hl[(kt * 32 + hrow + i) * GSZ + ht * 16 + hcol];

    // B operand = x^T tile: lane holds x[tok=lane&15][k=(lane>>4)*8+i]
    const int tokl  = lane & 15;
    const int acolk = (lane >> 4) * 8;
    // C/D layout [m89]: col = lane&15 = token, row = (lane>>4)*4+j = h quad
    const int hq    = (lane >> 4) * 4;

    const int tok0 = tb * TOK_PER_BLK + wave * 64;

    #pragma unroll
    for (int tt = 0; tt < 4; ++tt) {
        const int tbase = tok0 + tt * 16;

        // ---- load + convert x fragments (2 K-tiles of 32) ----
        bf16x8 xfrag[2];
        const float* __restrict__ xp =
            x + (size_t)(tbase + tokl) * DIM + g * GSZ + acolk;
        #pragma unroll
        for (int kt = 0; kt < 2; ++kt) {
            f32x4 lo = *(const f32x4*)(xp + kt * 32);
            f32x4 hi = *(const f32x4*)(xp + kt * 32 + 4);
            #pragma unroll
            for (int i = 0; i < 4; ++i) {
                xfrag[kt][i]     = (__bf16)lo[i];
                xfrag[kt][i + 4] = (__bf16)hi[i];
            }
        }

        // ---- 8 MFMAs: D[h][tok] = sum_k H^T[h][k] x^T[k][tok] ----
        f32x4 acc[4];
        #pragma unroll
        for (int ht = 0; ht < 4; ++ht) {
            acc[ht] = (f32x4){0.f, 0.f, 0.f, 0.f};
            acc[ht] = __builtin_amdgcn_mfma_f32_16x16x32_bf16(
                          hfrag[0][ht], xfrag[0], acc[ht], 0, 0, 0);
            acc[ht] = __builtin_amdgcn_mfma_f32_16x16x32_bf16(
                          hfrag[1][ht], xfrag[1], acc[ht], 0, 0, 0);
        }

        // ---- store: acc[ht] = y[tbase+tokl][g*64 + ht*16 + hq .. +3] ----
        float* __restrict__ yp =
            y + (size_t)(tbase + tokl) * DIM + g * GSZ + hq;
        #pragma unroll
        for (int ht = 0; ht < 4; ++ht)
            __builtin_nontemporal_store(acc[ht], (f32x4*)(yp + ht * 16));
    }
}

extern "C" void kernel_launch(void* const* d_in, const int* in_sizes, int n_in,
                              void* d_out, int out_size, void* d_ws, size_t ws_size,
                              hipStream_t stream) {
    const float* x = (const float*)d_in[0];
    const float* H = (const float*)d_in[1];
    float* y = (float*)d_out;

    const int ntok = in_sizes[0] / DIM;             // 16384
    const int nblk = (ntok / TOK_PER_BLK) * NG;     // 64 * 64 = 4096

    hipLaunchKernelGGL(hh_mfma_kernel, dim3(nblk), dim3(256), 0, stream,
                       x, H, y, ntok);
}

// Round 4
// 98.929 us; speedup vs baseline: 1.2219x; 1.0092x over previous
//
#include <hip/hip_runtime.h>
#include <hip/hip_bf16.h>

// y[n,g,h] = sum_k x[n,g,k] * H[g,k,h]
// x: [ntok, 4096] fp32, H: [64, 64, 64] fp32, y: [ntok, 4096] fp32.
// Memory-bound. R4: no LDS at all (hfrags direct from L2-resident H_g),
// register double-buffered x tiles (loads for t+1 in flight during t's
// MFMA+store), 512 tokens/block to amortize the fragment-build prologue.

#define DIM 4096
#define NG   64   // groups per token
#define GSZ  64   // group size
#define TOK_PER_BLK 512
#define TILES 8   // 16-token tiles per wave: 512 / 4 waves / 16

typedef __bf16 bf16x8 __attribute__((ext_vector_type(8)));
typedef float  f32x4  __attribute__((ext_vector_type(4)));

__global__ __launch_bounds__(256, 4)
void hh_mfma_kernel(const float* __restrict__ x, const float* __restrict__ H,
                    float* __restrict__ y, int ntok) {
    const int g    = blockIdx.x & (NG - 1);
    const int tb   = blockIdx.x >> 6;
    const int lane = threadIdx.x & 63;
    const int wave = threadIdx.x >> 6;

    // ---- build H^T fragments (A operand) straight from global (L2-hot) ----
    // hfrag[kt][ht][i] = H_g[kt*32 + (lane>>4)*8 + i][ht*16 + (lane&15)]
    const int hcol = lane & 15;
    const int hrow = (lane >> 4) * 8;
    const float* __restrict__ Hg = H + (size_t)g * (GSZ * GSZ);
    bf16x8 hfrag[2][4];
    #pragma unroll
    for (int kt = 0; kt < 2; ++kt)
        #pragma unroll
        for (int ht = 0; ht < 4; ++ht)
            #pragma unroll
            for (int i = 0; i < 8; ++i)
                hfrag[kt][ht][i] =
                    (__bf16)Hg[(kt * 32 + hrow + i) * GSZ + ht * 16 + hcol];

    // B operand = x^T tile: lane holds x[tok=lane&15][k=(lane>>4)*8+i]
    const int tokl  = lane & 15;
    const int acolk = (lane >> 4) * 8;
    const int hq    = (lane >> 4) * 4;   // C/D: col=token, row=4 consecutive h

    const int tok0 = tb * TOK_PER_BLK + wave * (16 * TILES);
    const float* __restrict__ xb =
        x + (size_t)(tok0 + tokl) * DIM + g * GSZ + acolk;
    float* __restrict__ yb =
        y + (size_t)(tok0 + tokl) * DIM + g * GSZ + hq;

    // raw[parity][4]: one tile = 4 f32x4 (lane's 32B x 2 k-tiles)
    f32x4 raw[2][4];

    // prologue: load tile 0
    #pragma unroll
    for (int kt = 0; kt < 2; ++kt) {
        raw[0][kt * 2 + 0] = *(const f32x4*)(xb + kt * 32);
        raw[0][kt * 2 + 1] = *(const f32x4*)(xb + kt * 32 + 4);
    }

    #pragma unroll
    for (int tt = 0; tt < TILES; ++tt) {
        // ---- issue next tile's loads first (hide latency under compute) ----
        if (tt + 1 < TILES) {
            const float* __restrict__ xp = xb + (size_t)(tt + 1) * 16 * DIM;
            #pragma unroll
            for (int kt = 0; kt < 2; ++kt) {
                raw[(tt + 1) & 1][kt * 2 + 0] = *(const f32x4*)(xp + kt * 32);
                raw[(tt + 1) & 1][kt * 2 + 1] = *(const f32x4*)(xp + kt * 32 + 4);
            }
        }

        // ---- convert current tile to bf16 fragments ----
        bf16x8 xfrag[2];
        #pragma unroll
        for (int kt = 0; kt < 2; ++kt)
            #pragma unroll
            for (int i = 0; i < 4; ++i) {
                xfrag[kt][i]     = (__bf16)raw[tt & 1][kt * 2 + 0][i];
                xfrag[kt][i + 4] = (__bf16)raw[tt & 1][kt * 2 + 1][i];
            }

        // ---- 8 MFMAs: D[h][tok] = sum_k H^T[h][k] x^T[k][tok] ----
        f32x4 acc[4];
        #pragma unroll
        for (int ht = 0; ht < 4; ++ht) {
            acc[ht] = (f32x4){0.f, 0.f, 0.f, 0.f};
            acc[ht] = __builtin_amdgcn_mfma_f32_16x16x32_bf16(
                          hfrag[0][ht], xfrag[0], acc[ht], 0, 0, 0);
            acc[ht] = __builtin_amdgcn_mfma_f32_16x16x32_bf16(
                          hfrag[1][ht], xfrag[1], acc[ht], 0, 0, 0);
        }

        // ---- store: lane writes 4 consecutive h per instr, NT (y not reread,
        //      and bypassing L3 keeps x resident there) ----
        float* __restrict__ yp = yb + (size_t)tt * 16 * DIM;
        #pragma unroll
        for (int ht = 0; ht < 4; ++ht)
            __builtin_nontemporal_store(acc[ht], (f32x4*)(yp + ht * 16));
    }
}

extern "C" void kernel_launch(void* const* d_in, const int* in_sizes, int n_in,
                              void* d_out, int out_size, void* d_ws, size_t ws_size,
                              hipStream_t stream) {
    const float* x = (const float*)d_in[0];
    const float* H = (const float*)d_in[1];
    float* y = (float*)d_out;

    const int ntok = in_sizes[0] / DIM;             // 16384
    const int nblk = (ntok / TOK_PER_BLK) * NG;     // 32 * 64 = 2048

    hipLaunchKernelGGL(hh_mfma_kernel, dim3(nblk), dim3(256), 0, stream,
                       x, H, y, ntok);
}